// Round 12
// baseline (214.662 us; speedup 1.0000x reference)
//
#include <hip/hip_runtime.h>
#include <hip/hip_bf16.h>

// ---------------------------------------------------------------------------
// EnhancedGNN: 2-layer GCN + linear head + sigmoid.
// R12: feature-sliced gather — tp stored as 4 column slices of n x 16 (3.2 MB,
//      fits one XCD L2). One dispatch, pass = blockIdx/bpp: per pass all edges
//      are aggregated for a 16-feature slice (relu+dot separable per slice),
//      z accumulated across passes via zpart + zsum. 8 edges x 8 lanes, uint
//      (2-feature) loads. Rest (CSR build, MFMA gemm1, folds) as R11.
// ---------------------------------------------------------------------------

#define EPB 4096      // edges per partition/count block
#define NBMAX 512     // max buckets (n/256) handled by the fast path

typedef __attribute__((ext_vector_type(8))) short bf16x8;
typedef __attribute__((ext_vector_type(4))) float f32x4;

__device__ __forceinline__ unsigned short f2b(float f) {   // fp32->bf16 RNE
    unsigned u = __builtin_bit_cast(unsigned, f);
    u += 0x7fffu + ((u >> 16) & 1u);
    return (unsigned short)(u >> 16);
}
__device__ __forceinline__ float b2f(unsigned short h) {
    unsigned u = (unsigned)h << 16;
    return __builtin_bit_cast(float, u);
}
__device__ __forceinline__ float blo(unsigned u) {         // low bf16 of dword
    return __builtin_bit_cast(float, u << 16);
}
__device__ __forceinline__ float bhi(unsigned u) {         // high bf16 of dword
    return __builtin_bit_cast(float, u & 0xffff0000u);
}

// ---------------- CSR build ----------------

__global__ __launch_bounds__(256) void bcount_k(
    const int* __restrict__ dst, int* __restrict__ bucket_cnt, int E, int nbuckets) {
    __shared__ int lh[NBMAX];
    int t = threadIdx.x;
    for (int i = t; i < nbuckets; i += 256) lh[i] = 0;
    __syncthreads();
    int e0 = blockIdx.x * EPB;
    int cnt = min(EPB, E - e0);
    for (int i = t; i < cnt; i += 256) atomicAdd(&lh[dst[e0 + i] >> 8], 1);
    __syncthreads();
    for (int i = t; i < nbuckets; i += 256)
        if (lh[i]) atomicAdd(&bucket_cnt[i], lh[i]);
}

// Exclusive scan of bucket counts -> base[0..nb] (base[nb]=E) and cur[] copy.
__global__ __launch_bounds__(512) void bscan_k(
    const int* __restrict__ cnt, int* __restrict__ base, int* __restrict__ cur, int nb) {
    __shared__ int s[512];
    int t = threadIdx.x;
    int v = (t < nb) ? cnt[t] : 0;
    s[t] = v; __syncthreads();
    #pragma unroll
    for (int off = 1; off < 512; off <<= 1) {
        int u = (t >= off) ? s[t - off] : 0;
        __syncthreads();
        s[t] += u;
        __syncthreads();
    }
    if (t < nb) { int e = s[t] - v; base[t] = e; cur[t] = e; }
    if (t == nb - 1) base[nb] = s[t];
}

// Partition edges into dst-bucket-clustered staging. Packed: src | dstLow<<17.
__global__ __launch_bounds__(256) void partition_k(
    const int* __restrict__ src, const int* __restrict__ dst,
    int* __restrict__ bucket_cur, int* __restrict__ stage, int E, int nbuckets) {
    __shared__ int ls[EPB];
    __shared__ int ld[EPB];
    __shared__ int lhist[NBMAX];
    __shared__ int lbase[NBMAX];
    int e0 = blockIdx.x * EPB;
    int cnt = min(EPB, E - e0);
    int t = threadIdx.x;
    for (int i = t; i < cnt; i += 256) { ls[i] = src[e0 + i]; ld[i] = dst[e0 + i]; }
    for (int b = t; b < nbuckets; b += 256) lhist[b] = 0;
    __syncthreads();
    for (int i = t; i < cnt; i += 256) atomicAdd(&lhist[ld[i] >> 8], 1);
    __syncthreads();
    for (int b = t; b < nbuckets; b += 256) {
        int c = lhist[b];
        lbase[b] = (c > 0) ? atomicAdd(&bucket_cur[b], c) : 0;
        lhist[b] = 0;
    }
    __syncthreads();
    for (int i = t; i < cnt; i += 256) {
        int d  = ld[i];
        int b  = d >> 8;
        int off = atomicAdd(&lhist[b], 1);
        stage[lbase[b] + off] = ls[i] | ((d & 255) << 17);
    }
}

// One block per bucket: per-node LDS hist + scan -> row_start, dis, placement.
__global__ __launch_bounds__(256) void bucket_place_k(
    const int* __restrict__ stage, const int* __restrict__ bucket_base,
    int* __restrict__ row_start, float* __restrict__ dis,
    int* __restrict__ csr_src, int n, int nbuckets) {
    __shared__ int lh[256];
    __shared__ int ss[256];
    __shared__ int lcur[256];
    int b = blockIdx.x;
    int t = threadIdx.x;
    int ebeg = bucket_base[b], eend = bucket_base[b + 1];
    int node0 = b << 8;

    lh[t] = 0;
    __syncthreads();
    for (int e = ebeg + t; e < eend; e += 256)
        atomicAdd(&lh[(stage[e] >> 17) & 255], 1);
    __syncthreads();

    int cnt = lh[t];
    ss[t] = cnt;
    __syncthreads();
    #pragma unroll
    for (int off = 1; off < 256; off <<= 1) {
        int u = (t >= off) ? ss[t - off] : 0;
        __syncthreads();
        ss[t] += u;
        __syncthreads();
    }
    int excl = ss[t] - cnt;
    int node = node0 + t;
    if (node < n) {
        row_start[node] = ebeg + excl;
        dis[node] = rsqrtf((float)cnt + 1.0f);
    }
    lcur[t] = ebeg + excl;
    if (b == nbuckets - 1 && t == 0) row_start[n] = eend;
    __syncthreads();

    for (int e = ebeg + t; e < eend; e += 256) {
        int p = stage[e];
        int pos = atomicAdd(&lcur[(p >> 17) & 255], 1);
        csr_src[pos] = p & 0x1FFFF;
    }
}

// ---------------- W1 frag pack + w2l + c0 + bcnt zero (one small launch) -----
__global__ void wfrag_k(const float* __restrict__ W1, const float* __restrict__ W2,
                        unsigned short* __restrict__ fw1, float* __restrict__ w2l,
                        const float* __restrict__ b2, const float* __restrict__ Wl,
                        const float* __restrict__ bl, float* __restrict__ c0,
                        int* __restrict__ bcnt) {
    int gid = blockIdx.x * blockDim.x + threadIdx.x;
    if (gid <= NBMAX) bcnt[gid] = 0;                       // zero bucket counters
    if (blockIdx.x == 0 && threadIdx.x < 64) {             // c0 = dot(b2,Wl)+bl
        float v = b2[threadIdx.x] * Wl[threadIdx.x];
        #pragma unroll
        for (int m = 32; m >= 1; m >>= 1) v += __shfl_xor(v, m);
        if (threadIdx.x == 0) c0[0] = v + bl[0];
    }
    if (blockIdx.x == 1 && threadIdx.x < 64) {             // w2l = W2 @ Wl
        int k = threadIdx.x;
        float s = 0.f;
        #pragma unroll 8
        for (int j = 0; j < 64; ++j) s = fmaf(W2[k * 64 + j], Wl[j], s);
        w2l[k] = s;
    }
    if (gid < 8192) {                                      // W1 B-fragments
        int f = gid >> 9, rem = gid & 511;
        int l = rem >> 3, i = rem & 7;
        int ks = f >> 2, ct = f & 3;
        int k = ks * 32 + ((l >> 4) << 3) + i;
        int c = ct * 16 + (l & 15);
        fw1[gid] = f2b(W1[k * 64 + c]);
    }
}

// ---------------- MFMA GEMM1 -> column-sliced tp --------------------------
// Slice ct (cols 16ct..16ct+15) stored at Y + ct*n*16 + row*16 + col.
template <int K>
__global__ __launch_bounds__(256) void mfma_gemm_k(
    const float* __restrict__ X, const unsigned short* __restrict__ FW,
    const float* __restrict__ dis, unsigned short* __restrict__ Y, int n) {
    constexpr int KS = K / 32;
    int wave   = (int)((blockIdx.x * blockDim.x + threadIdx.x) >> 6);
    int lane   = threadIdx.x & 63;
    int nwaves = (int)((gridDim.x * blockDim.x) >> 6);
    int ntiles = n >> 4;
    size_t n16 = (size_t)n * 16;

    bf16x8 bfrag[KS][4];
    #pragma unroll
    for (int ks = 0; ks < KS; ++ks)
        #pragma unroll
        for (int ct = 0; ct < 4; ++ct)
            bfrag[ks][ct] = *reinterpret_cast<const bf16x8*>(FW + ((ks * 4 + ct) << 9) + (lane << 3));

    int rb = lane & 15;
    int kb = (lane >> 4) << 3;

    for (int tile = wave; tile < ntiles; tile += nwaves) {
        int row = (tile << 4) + rb;
        f32x4 acc[4];
        #pragma unroll
        for (int ct = 0; ct < 4; ++ct) acc[ct] = (f32x4){0.f, 0.f, 0.f, 0.f};

        #pragma unroll
        for (int ks = 0; ks < KS; ++ks) {
            const float* p = X + (size_t)row * K + ks * 32 + kb;
            float4 u = *reinterpret_cast<const float4*>(p);
            float4 v = *reinterpret_cast<const float4*>(p + 4);
            bf16x8 af;
            af[0] = (short)f2b(u.x); af[1] = (short)f2b(u.y);
            af[2] = (short)f2b(u.z); af[3] = (short)f2b(u.w);
            af[4] = (short)f2b(v.x); af[5] = (short)f2b(v.y);
            af[6] = (short)f2b(v.z); af[7] = (short)f2b(v.w);
            #pragma unroll
            for (int ct = 0; ct < 4; ++ct)
                acc[ct] = __builtin_amdgcn_mfma_f32_16x16x32_bf16(af, bfrag[ks][ct], acc[ct], 0, 0, 0);
        }

        int orow0 = (tile << 4) + ((lane >> 4) << 2);
        int ocol  = lane & 15;
        float dv0 = dis[orow0], dv1 = dis[orow0 + 1], dv2 = dis[orow0 + 2], dv3 = dis[orow0 + 3];
        #pragma unroll
        for (int ct = 0; ct < 4; ++ct) {
            unsigned short* yp = Y + (size_t)ct * n16 + (size_t)orow0 * 16 + ocol;
            yp[0]  = f2b(acc[ct][0] * dv0);
            yp[16] = f2b(acc[ct][1] * dv1);
            yp[32] = f2b(acc[ct][2] * dv2);
            yp[48] = f2b(acc[ct][3] * dv3);
        }
    }
}

// ---------------- feature-sliced fused gather1 -> zpart ----------------------
// pass p covers features [16p, 16p+16); per wave: 8 edges x 8 lanes, each lane
// loads uint = 2 bf16 features. agg complete per slice -> relu -> partial dot
// with w2l -> zpart[p*n + node]. 4 nodes per block.
__global__ __launch_bounds__(256) void gather_k(
    const int* __restrict__ row_start, const int* __restrict__ csr_src,
    const float* __restrict__ dis, const unsigned short* __restrict__ tp,
    const float* __restrict__ b, const float* __restrict__ w2l,
    float* __restrict__ zpart, int n, int bpp) {
    int blk  = blockIdx.x;
    int pass = blk / bpp;
    int node = ((blk % bpp) << 2) + (threadIdx.x >> 6);
    int lane = threadIdx.x & 63;
    if (node >= n) return;
    int eo = lane >> 3;        // edge slot (0..7)
    int fh = lane & 7;         // feature half-pair (features 2fh, 2fh+1 of slice)
    int beg = row_start[node], end = row_start[node + 1];
    float dd = dis[node];
    const unsigned short* tpp = tp + (size_t)pass * n * 16;

    float a0 = 0.f, a1 = 0.f;
    if (eo == 0) {             // self term (rows pre-scaled by dis)
        unsigned u = *reinterpret_cast<const unsigned*>(tpp + (size_t)node * 16 + fh * 2);
        a0 = blo(u); a1 = bhi(u);
    }

    for (int base = beg; base < end; base += 64) {
        int rem = end - base;
        int cnt = rem < 64 ? rem : 64;
        int idx = (lane < cnt) ? csr_src[base + lane] : 0;   // coalesced window
        for (int j = 0; j < cnt; j += 8) {
            int s = __shfl(idx, j + eo);
            if (j + eo < cnt) {
                unsigned u = *reinterpret_cast<const unsigned*>(tpp + (size_t)s * 16 + fh * 2);
                a0 += blo(u); a1 += bhi(u);
            }
        }
    }

    // sum the 8 edge slots
    a0 += __shfl_xor(a0, 8);  a1 += __shfl_xor(a1, 8);
    a0 += __shfl_xor(a0, 16); a1 += __shfl_xor(a1, 16);
    a0 += __shfl_xor(a0, 32); a1 += __shfl_xor(a1, 32);

    int f0 = (pass << 4) + (fh << 1);
    float h0 = fmaxf(fmaf(dd, a0, b[f0]), 0.f);
    float h1 = fmaxf(fmaf(dd, a1, b[f0 + 1]), 0.f);
    float v = fmaf(h0, w2l[f0], h1 * w2l[f0 + 1]);
    v += __shfl_xor(v, 1); v += __shfl_xor(v, 2); v += __shfl_xor(v, 4);
    if (lane == 0) zpart[(size_t)pass * n + node] = dd * v;
}

// z[i] = sum of 4 pass partials
__global__ void zsum_k(const float* __restrict__ zp, float* __restrict__ z, int n) {
    int i = blockIdx.x * blockDim.x + threadIdx.x;
    if (i < n)
        z[i] = (zp[i] + zp[(size_t)n + i]) + (zp[2 * (size_t)n + i] + zp[3 * (size_t)n + i]);
}

// ---------------- layer-2 scalar gather + sigmoid (head folded) -------------
__global__ __launch_bounds__(256) void gatherz_k(
    const int* __restrict__ row_start, const int* __restrict__ csr_src,
    const float* __restrict__ dis, const float* __restrict__ z,
    const float* __restrict__ c0, float* __restrict__ out, int n) {
    int i = blockIdx.x * blockDim.x + threadIdx.x;
    if (i >= n) return;
    int beg = row_start[i], end = row_start[i + 1];
    float s0 = 0.f, s1 = 0.f, s2 = 0.f, s3 = 0.f;
    int e = beg;
    for (; e + 4 <= end; e += 4) {
        s0 += z[csr_src[e + 0]];
        s1 += z[csr_src[e + 1]];
        s2 += z[csr_src[e + 2]];
        s3 += z[csr_src[e + 3]];
    }
    for (; e < end; ++e) s0 += z[csr_src[e]];
    float v = fmaf(dis[i], z[i] + ((s0 + s1) + (s2 + s3)), c0[0]);
    out[i] = 1.f / (1.f + expf(-v));
}

// ---------------- fallback kernels (only if ws too small / shape odd) --------

__global__ void relu_k(float* __restrict__ p, long long m) {
    long long i = (long long)blockIdx.x * blockDim.x + threadIdx.x;
    if (i < m) p[i] = fmaxf(p[i], 0.f);
}
__global__ void deg_init_k(float* __restrict__ deg, int n) {
    int i = blockIdx.x * blockDim.x + threadIdx.x;
    if (i < n) deg[i] = 1.0f;
}
__global__ void deg_edges_k(const int* __restrict__ dst, float* __restrict__ deg, int E) {
    int e = blockIdx.x * blockDim.x + threadIdx.x;
    if (e < E) atomicAdd(&deg[dst[e]], 1.0f);
}
__global__ void dis_k(float* __restrict__ deg, int n) {
    int i = blockIdx.x * blockDim.x + threadIdx.x;
    if (i < n) deg[i] = rsqrtf(deg[i]);
}
__global__ void init_agg_k(const float* __restrict__ t, const float* __restrict__ dis,
                           const float* __restrict__ b, float* __restrict__ agg, int n) {
    int idx = blockIdx.x * blockDim.x + threadIdx.x;
    if (idx >= n * 64) return;
    int i = idx >> 6, jj = idx & 63;
    float ds = dis[i];
    agg[idx] = ds * ds * t[idx] + b[jj];
}
__global__ __launch_bounds__(256) void agg_edges_k(
    const int* __restrict__ src, const int* __restrict__ dst,
    const float* __restrict__ dis, const float* __restrict__ t,
    float* __restrict__ agg, int E) {
    int e    = (int)((blockIdx.x * blockDim.x + threadIdx.x) >> 6);
    int lane = threadIdx.x & 63;
    if (e >= E) return;
    int s = src[e], d = dst[e];
    float w = dis[s] * dis[d];
    atomicAdd(&agg[(size_t)d * 64 + lane], w * t[(size_t)s * 64 + lane]);
}
__global__ __launch_bounds__(256) void final_k(
    const float* __restrict__ agg, const float* __restrict__ Wl,
    const float* __restrict__ bl, float* __restrict__ out, int n) {
    int node = (int)((blockIdx.x * blockDim.x + threadIdx.x) >> 6);
    int lane = threadIdx.x & 63;
    if (node >= n) return;
    float v = agg[(size_t)node * 64 + lane] * Wl[lane];
    #pragma unroll
    for (int m = 32; m >= 1; m >>= 1) v += __shfl_xor(v, m);
    if (lane == 0) out[node] = 1.f / (1.f + expf(-(v + bl[0])));
}
template <int K>
__global__ __launch_bounds__(256) void gemm_rows4_k(
    const float* __restrict__ X, const float* __restrict__ W,
    float* __restrict__ Y, int n) {
    __shared__ float Ws[K * 64];
    for (int t = threadIdx.x; t < K * 64; t += blockDim.x) Ws[t] = W[t];
    __syncthreads();
    int wave   = (int)((blockIdx.x * blockDim.x + threadIdx.x) >> 6);
    int lane   = threadIdx.x & 63;
    int nwaves = (int)((gridDim.x * blockDim.x) >> 6);
    for (int r = wave; r < n; r += nwaves) {
        const float* xr = X + (size_t)r * K;
        float acc = 0.f;
        for (int k = 0; k < K; k += 4) {
            float4 a = *reinterpret_cast<const float4*>(xr + k);
            acc = fmaf(a.x, Ws[(k + 0) * 64 + lane], acc);
            acc = fmaf(a.y, Ws[(k + 1) * 64 + lane], acc);
            acc = fmaf(a.z, Ws[(k + 2) * 64 + lane], acc);
            acc = fmaf(a.w, Ws[(k + 3) * 64 + lane], acc);
        }
        Y[(size_t)r * 64 + lane] = acc;
    }
}

// ---------------------------------------------------------------------------

extern "C" void kernel_launch(void* const* d_in, const int* in_sizes, int n_in,
                              void* d_out, int out_size, void* d_ws, size_t ws_size,
                              hipStream_t stream) {
    const float* x  = (const float*)d_in[0];
    const int*   ei = (const int*)d_in[1];
    const float* W1 = (const float*)d_in[2];
    const float* b1 = (const float*)d_in[3];
    const float* W2 = (const float*)d_in[4];
    const float* b2 = (const float*)d_in[5];
    const float* Wl = (const float*)d_in[6];
    const float* bl = (const float*)d_in[7];
    float* out = (float*)d_out;

    const int n = in_sizes[0] / 128;      // 100000
    const int E = in_sizes[1] / 2;        // 1600000
    const int* src = ei;
    const int* dst = ei + E;

    const int B = 256;
    dim3 blk(B);
    auto align512 = [](size_t v) { return (v + 511) & ~(size_t)511; };

    // workspace layout
    char* ws = (char*)d_ws;
    size_t off = 0;
    float*          dis     = (float*)(ws + off); off = align512(off + (size_t)n * 4);
    int*            row_st  = (int*)  (ws + off); off = align512(off + (size_t)(n + 1) * 4);
    int*            bcnt    = (int*)  (ws + off); off = align512(off + (size_t)(NBMAX + 1) * 4);
    int*            bbase   = (int*)  (ws + off); off = align512(off + (size_t)(NBMAX + 1) * 4);
    int*            bcur    = (int*)  (ws + off); off = align512(off + (size_t)NBMAX * 4);
    float*          c0      = (float*)(ws + off); off = align512(off + 512);
    float*          w2l     = (float*)(ws + off); off = align512(off + 64 * 4);
    float*          zpart   = (float*)(ws + off); off = align512(off + (size_t)n * 4 * 4);
    float*          zbuf    = (float*)(ws + off); off = align512(off + (size_t)n * 4);
    int*            csr_src = (int*)  (ws + off); off = align512(off + (size_t)E * 4);
    unsigned short* bufA16  = (unsigned short*)(ws + off); off = align512(off + (size_t)n * 64 * 2);
    int*            stage   = (int*)  (ws + off); off = align512(off + (size_t)E * 4);
    unsigned short* fw1     = (unsigned short*)(ws + off); off = align512(off + 8192 * 2);
    size_t need_csr = off;

    const int nbuckets = (n + 255) >> 8;
    const int nebl = (E + EPB - 1) / EPB;   // edge blocks

    if (ws_size >= need_csr && (n & 15) == 0 && nbuckets <= NBMAX && n <= (1 << 17)) {
        // ---- W1 frag pack + w2l + c0 + bcnt zero (one small launch) ----
        wfrag_k<<<48, blk, 0, stream>>>(W1, W2, fw1, w2l, b2, Wl, bl, c0, bcnt);

        // ---- CSR build (LDS-privatized, no hot global atomics) ----
        bcount_k<<<nebl, blk, 0, stream>>>(dst, bcnt, E, nbuckets);
        bscan_k<<<1, 512, 0, stream>>>(bcnt, bbase, bcur, nbuckets);
        partition_k<<<nebl, blk, 0, stream>>>(src, dst, bcur, stage, E, nbuckets);
        bucket_place_k<<<nbuckets, blk, 0, stream>>>(stage, bbase, row_st, dis, csr_src, n, nbuckets);

        int gemm_blocks = ((n >> 4) + 3) / 4;   // one wave per 16-row tile

        // ---- layer 1 GEMM: column-sliced tp = bf16(dis * (x @ W1)) ----
        mfma_gemm_k<128><<<gemm_blocks, blk, 0, stream>>>(x, fw1, dis, bufA16, n);

        // ---- feature-sliced fused gather1 (+relu, +W2@Wl dot) -> zpart ----
        int bpp = (n + 3) >> 2;                 // blocks per pass (4 nodes/block)
        gather_k<<<4 * bpp, blk, 0, stream>>>(
            row_st, csr_src, dis, bufA16, b1, w2l, zpart, n, bpp);
        zsum_k<<<(n + B - 1) / B, blk, 0, stream>>>(zpart, zbuf, n);

        // ---- layer-2 scalar aggregation + sigmoid ----
        gatherz_k<<<(n + B - 1) / B, blk, 0, stream>>>(
            row_st, csr_src, dis, zbuf, c0, out, n);
    } else {
        // ---- fallback: atomic scatter, fp32 GEMM ----
        size_t o2 = 0;
        float* dis2 = (float*)(ws + o2); o2 = align512(o2 + (size_t)n * 4);
        float* bA   = (float*)(ws + o2); o2 += (size_t)n * 64 * 4;
        float* bB   = (float*)(ws + o2);

        deg_init_k<<<(n + B - 1) / B, blk, 0, stream>>>(dis2, n);
        deg_edges_k<<<(E + B - 1) / B, blk, 0, stream>>>(dst, dis2, E);
        dis_k<<<(n + B - 1) / B, blk, 0, stream>>>(dis2, n);

        gemm_rows4_k<128><<<2048, blk, 0, stream>>>(x, W1, bA, n);
        init_agg_k<<<((size_t)n * 64 + B - 1) / B, blk, 0, stream>>>(bA, dis2, b1, bB, n);
        agg_edges_k<<<(E + 3) / 4, blk, 0, stream>>>(src, dst, dis2, bA, bB, E);
        relu_k<<<((size_t)n * 64 + B - 1) / B, blk, 0, stream>>>(bB, (long long)n * 64);

        gemm_rows4_k<64><<<2048, blk, 0, stream>>>(bB, W2, bA, n);
        init_agg_k<<<((size_t)n * 64 + B - 1) / B, blk, 0, stream>>>(bA, dis2, b2, bB, n);
        agg_edges_k<<<(E + 3) / 4, blk, 0, stream>>>(src, dst, dis2, bA, bB, E);

        final_k<<<(n + 3) / 4, blk, 0, stream>>>(bB, Wl, bl, out, n);
    }
}

// Round 13
// 132.236 us; speedup vs baseline: 1.6233x; 1.6233x over previous
//
#include <hip/hip_runtime.h>
#include <hip/hip_bf16.h>

// ---------------------------------------------------------------------------
// EnhancedGNN: 2-layer GCN + linear head + sigmoid.
// R13: revert to R11 structure (64-lane/edge gather — proven shape), plus
//      src-tile counting-sort of each node's adjacency list in bucket_place
//      (tile = src>>14, <=8 tiles x 2MB tp slices): concurrent waves sweep tp
//      in phase -> higher L2 hit on the gather. CSR semantics unchanged.
//      Algebraic folds as R11: z in gather epilogue via w2l=W2@Wl; gemm2 gone.
// ---------------------------------------------------------------------------

#define EPB 4096      // edges per partition/count block
#define NBMAX 512     // max buckets (n/256) handled by the fast path

typedef __attribute__((ext_vector_type(8))) short bf16x8;
typedef __attribute__((ext_vector_type(4))) float f32x4;

__device__ __forceinline__ unsigned short f2b(float f) {   // fp32->bf16 RNE
    unsigned u = __builtin_bit_cast(unsigned, f);
    u += 0x7fffu + ((u >> 16) & 1u);
    return (unsigned short)(u >> 16);
}
__device__ __forceinline__ float b2f(unsigned short h) {
    unsigned u = (unsigned)h << 16;
    return __builtin_bit_cast(float, u);
}

// ---------------- CSR build ----------------

__global__ __launch_bounds__(256) void bcount_k(
    const int* __restrict__ dst, int* __restrict__ bucket_cnt, int E, int nbuckets) {
    __shared__ int lh[NBMAX];
    int t = threadIdx.x;
    for (int i = t; i < nbuckets; i += 256) lh[i] = 0;
    __syncthreads();
    int e0 = blockIdx.x * EPB;
    int cnt = min(EPB, E - e0);
    for (int i = t; i < cnt; i += 256) atomicAdd(&lh[dst[e0 + i] >> 8], 1);
    __syncthreads();
    for (int i = t; i < nbuckets; i += 256)
        if (lh[i]) atomicAdd(&bucket_cnt[i], lh[i]);
}

// Exclusive scan of bucket counts -> base[0..nb] (base[nb]=E) and cur[] copy.
__global__ __launch_bounds__(512) void bscan_k(
    const int* __restrict__ cnt, int* __restrict__ base, int* __restrict__ cur, int nb) {
    __shared__ int s[512];
    int t = threadIdx.x;
    int v = (t < nb) ? cnt[t] : 0;
    s[t] = v; __syncthreads();
    #pragma unroll
    for (int off = 1; off < 512; off <<= 1) {
        int u = (t >= off) ? s[t - off] : 0;
        __syncthreads();
        s[t] += u;
        __syncthreads();
    }
    if (t < nb) { int e = s[t] - v; base[t] = e; cur[t] = e; }
    if (t == nb - 1) base[nb] = s[t];
}

// Partition edges into dst-bucket-clustered staging. Packed: src | dstLow<<17.
__global__ __launch_bounds__(256) void partition_k(
    const int* __restrict__ src, const int* __restrict__ dst,
    int* __restrict__ bucket_cur, int* __restrict__ stage, int E, int nbuckets) {
    __shared__ int ls[EPB];
    __shared__ int ld[EPB];
    __shared__ int lhist[NBMAX];
    __shared__ int lbase[NBMAX];
    int e0 = blockIdx.x * EPB;
    int cnt = min(EPB, E - e0);
    int t = threadIdx.x;
    for (int i = t; i < cnt; i += 256) { ls[i] = src[e0 + i]; ld[i] = dst[e0 + i]; }
    for (int b = t; b < nbuckets; b += 256) lhist[b] = 0;
    __syncthreads();
    for (int i = t; i < cnt; i += 256) atomicAdd(&lhist[ld[i] >> 8], 1);
    __syncthreads();
    for (int b = t; b < nbuckets; b += 256) {
        int c = lhist[b];
        lbase[b] = (c > 0) ? atomicAdd(&bucket_cur[b], c) : 0;
        lhist[b] = 0;
    }
    __syncthreads();
    for (int i = t; i < cnt; i += 256) {
        int d  = ld[i];
        int b  = d >> 8;
        int off = atomicAdd(&lhist[b], 1);
        stage[lbase[b] + off] = ls[i] | ((d & 255) << 17);
    }
}

// One block per bucket: per-node x per-src-tile LDS hist + scan -> row_start,
// dis, and placement with node lists internally ordered by src tile (src>>14).
__global__ __launch_bounds__(256) void bucket_place_k(
    const int* __restrict__ stage, const int* __restrict__ bucket_base,
    int* __restrict__ row_start, float* __restrict__ dis,
    int* __restrict__ csr_src, int n, int nbuckets) {
    __shared__ int lh[256 * 8];    // [node][tile] counts
    __shared__ int ss[256];
    __shared__ int lcur[256 * 8];
    int b = blockIdx.x;
    int t = threadIdx.x;
    int ebeg = bucket_base[b], eend = bucket_base[b + 1];
    int node0 = b << 8;

    #pragma unroll
    for (int k = 0; k < 8; ++k) lh[t * 8 + k] = 0;
    __syncthreads();
    for (int e = ebeg + t; e < eend; e += 256) {
        int p = stage[e];
        int sid = p & 0x1FFFF;
        atomicAdd(&lh[((p >> 17) & 255) * 8 + (sid >> 14)], 1);
    }
    __syncthreads();

    int cnt = 0;
    #pragma unroll
    for (int k = 0; k < 8; ++k) cnt += lh[t * 8 + k];
    ss[t] = cnt;
    __syncthreads();
    #pragma unroll
    for (int off = 1; off < 256; off <<= 1) {
        int u = (t >= off) ? ss[t - off] : 0;
        __syncthreads();
        ss[t] += u;
        __syncthreads();
    }
    int excl = ss[t] - cnt;
    int node = node0 + t;
    if (node < n) {
        row_start[node] = ebeg + excl;
        dis[node] = rsqrtf((float)cnt + 1.0f);
    }
    if (b == nbuckets - 1 && t == 0) row_start[n] = eend;
    int run = ebeg + excl;                 // within-node tile prefix
    #pragma unroll
    for (int k = 0; k < 8; ++k) { lcur[t * 8 + k] = run; run += lh[t * 8 + k]; }
    __syncthreads();

    for (int e = ebeg + t; e < eend; e += 256) {
        int p = stage[e];
        int sid = p & 0x1FFFF;
        int pos = atomicAdd(&lcur[((p >> 17) & 255) * 8 + (sid >> 14)], 1);
        csr_src[pos] = sid;
    }
}

// ---------------- W1 frag pack + w2l + c0 + bcnt zero (one small launch) -----
__global__ void wfrag_k(const float* __restrict__ W1, const float* __restrict__ W2,
                        unsigned short* __restrict__ fw1, float* __restrict__ w2l,
                        const float* __restrict__ b2, const float* __restrict__ Wl,
                        const float* __restrict__ bl, float* __restrict__ c0,
                        int* __restrict__ bcnt) {
    int gid = blockIdx.x * blockDim.x + threadIdx.x;
    if (gid <= NBMAX) bcnt[gid] = 0;                       // zero bucket counters
    if (blockIdx.x == 0 && threadIdx.x < 64) {             // c0 = dot(b2,Wl)+bl
        float v = b2[threadIdx.x] * Wl[threadIdx.x];
        #pragma unroll
        for (int m = 32; m >= 1; m >>= 1) v += __shfl_xor(v, m);
        if (threadIdx.x == 0) c0[0] = v + bl[0];
    }
    if (blockIdx.x == 1 && threadIdx.x < 64) {             // w2l = W2 @ Wl
        int k = threadIdx.x;
        float s = 0.f;
        #pragma unroll 8
        for (int j = 0; j < 64; ++j) s = fmaf(W2[k * 64 + j], Wl[j], s);
        w2l[k] = s;
    }
    if (gid < 8192) {                                      // W1 B-fragments
        int f = gid >> 9, rem = gid & 511;
        int l = rem >> 3, i = rem & 7;
        int ks = f >> 2, ct = f & 3;
        int k = ks * 32 + ((l >> 4) << 3) + i;
        int c = ct * 16 + (l & 15);
        fw1[gid] = f2b(W1[k * 64 + c]);
    }
}

// ---------------- MFMA GEMM1: Y[r,:] = bf16( dis[r] * (x[r,:] @ W1) ) --------
template <int K>
__global__ __launch_bounds__(256) void mfma_gemm_k(
    const float* __restrict__ X, const unsigned short* __restrict__ FW,
    const float* __restrict__ dis, unsigned short* __restrict__ Y, int n) {
    constexpr int KS = K / 32;
    int wave   = (int)((blockIdx.x * blockDim.x + threadIdx.x) >> 6);
    int lane   = threadIdx.x & 63;
    int nwaves = (int)((gridDim.x * blockDim.x) >> 6);
    int ntiles = n >> 4;

    bf16x8 bfrag[KS][4];
    #pragma unroll
    for (int ks = 0; ks < KS; ++ks)
        #pragma unroll
        for (int ct = 0; ct < 4; ++ct)
            bfrag[ks][ct] = *reinterpret_cast<const bf16x8*>(FW + ((ks * 4 + ct) << 9) + (lane << 3));

    int rb = lane & 15;
    int kb = (lane >> 4) << 3;

    for (int tile = wave; tile < ntiles; tile += nwaves) {
        int row = (tile << 4) + rb;
        f32x4 acc[4];
        #pragma unroll
        for (int ct = 0; ct < 4; ++ct) acc[ct] = (f32x4){0.f, 0.f, 0.f, 0.f};

        #pragma unroll
        for (int ks = 0; ks < KS; ++ks) {
            const float* p = X + (size_t)row * K + ks * 32 + kb;
            float4 u = *reinterpret_cast<const float4*>(p);
            float4 v = *reinterpret_cast<const float4*>(p + 4);
            bf16x8 af;
            af[0] = (short)f2b(u.x); af[1] = (short)f2b(u.y);
            af[2] = (short)f2b(u.z); af[3] = (short)f2b(u.w);
            af[4] = (short)f2b(v.x); af[5] = (short)f2b(v.y);
            af[6] = (short)f2b(v.z); af[7] = (short)f2b(v.w);
            #pragma unroll
            for (int ct = 0; ct < 4; ++ct)
                acc[ct] = __builtin_amdgcn_mfma_f32_16x16x32_bf16(af, bfrag[ks][ct], acc[ct], 0, 0, 0);
        }

        int orow0 = (tile << 4) + ((lane >> 4) << 2);
        int ocol  = lane & 15;
        float dv0 = dis[orow0], dv1 = dis[orow0 + 1], dv2 = dis[orow0 + 2], dv3 = dis[orow0 + 3];
        #pragma unroll
        for (int ct = 0; ct < 4; ++ct) {
            Y[(size_t)(orow0 + 0) * 64 + ct * 16 + ocol] = f2b(acc[ct][0] * dv0);
            Y[(size_t)(orow0 + 1) * 64 + ct * 16 + ocol] = f2b(acc[ct][1] * dv1);
            Y[(size_t)(orow0 + 2) * 64 + ct * 16 + ocol] = f2b(acc[ct][2] * dv2);
            Y[(size_t)(orow0 + 3) * 64 + ct * 16 + ocol] = f2b(acc[ct][3] * dv3);
        }
    }
}

// ---------------- fused gather1 + (relu, W2@Wl dot) -> z ---------------------
// Per node: agg = tp[node] + sum_{s in N} tp[s]  (tp rows pre-scaled by dis);
// h1 = relu(dd*agg + b1)  (fp32, registers only);
// z[node] = dd * dot(h1, w2l)  (butterfly reduce; single float store).
__global__ __launch_bounds__(256) void gather_k(
    const int* __restrict__ row_start, const int* __restrict__ csr_src,
    const float* __restrict__ dis, const unsigned short* __restrict__ tp,
    const float* __restrict__ b, const float* __restrict__ w2l,
    float* __restrict__ z, int n) {
    int node = (int)((blockIdx.x * blockDim.x + threadIdx.x) >> 6);
    int lane = threadIdx.x & 63;
    if (node >= n) return;
    int beg = row_start[node], end = row_start[node + 1];
    float dd = dis[node];
    float a0 = b2f(tp[(size_t)node * 64 + lane]);   // self term (pre-scaled)
    float a1 = 0.f, a2 = 0.f, a3 = 0.f, a4 = 0.f, a5 = 0.f, a6 = 0.f, a7 = 0.f;

    for (int base = beg; base < end; base += 64) {
        int rem = end - base;
        int cnt = rem < 64 ? rem : 64;
        int idx = (lane < cnt) ? csr_src[base + lane] : 0;   // coalesced window
        int j = 0;
        for (; j + 8 <= cnt; j += 8) {
            int s0 = __shfl(idx, j + 0), s1 = __shfl(idx, j + 1);
            int s2 = __shfl(idx, j + 2), s3 = __shfl(idx, j + 3);
            int s4 = __shfl(idx, j + 4), s5 = __shfl(idx, j + 5);
            int s6 = __shfl(idx, j + 6), s7 = __shfl(idx, j + 7);
            a0 += b2f(tp[(size_t)s0 * 64 + lane]);
            a1 += b2f(tp[(size_t)s1 * 64 + lane]);
            a2 += b2f(tp[(size_t)s2 * 64 + lane]);
            a3 += b2f(tp[(size_t)s3 * 64 + lane]);
            a4 += b2f(tp[(size_t)s4 * 64 + lane]);
            a5 += b2f(tp[(size_t)s5 * 64 + lane]);
            a6 += b2f(tp[(size_t)s6 * 64 + lane]);
            a7 += b2f(tp[(size_t)s7 * 64 + lane]);
        }
        if (j + 4 <= cnt) {
            int s0 = __shfl(idx, j + 0), s1 = __shfl(idx, j + 1);
            int s2 = __shfl(idx, j + 2), s3 = __shfl(idx, j + 3);
            a0 += b2f(tp[(size_t)s0 * 64 + lane]);
            a1 += b2f(tp[(size_t)s1 * 64 + lane]);
            a2 += b2f(tp[(size_t)s2 * 64 + lane]);
            a3 += b2f(tp[(size_t)s3 * 64 + lane]);
            j += 4;
        }
        for (; j < cnt; ++j) {
            int s = __shfl(idx, j);
            a4 += b2f(tp[(size_t)s * 64 + lane]);
        }
    }

    float acc = ((a0 + a1) + (a2 + a3)) + ((a4 + a5) + (a6 + a7));
    float h = fmaxf(fmaf(dd, acc, b[lane]), 0.f);   // h1[node][lane], fp32
    float v = h * w2l[lane];
    #pragma unroll
    for (int m = 32; m >= 1; m >>= 1) v += __shfl_xor(v, m);
    if (lane == 0) z[node] = dd * v;
}

// ---------------- layer-2 scalar gather + sigmoid (head folded) -------------
__global__ __launch_bounds__(256) void gatherz_k(
    const int* __restrict__ row_start, const int* __restrict__ csr_src,
    const float* __restrict__ dis, const float* __restrict__ z,
    const float* __restrict__ c0, float* __restrict__ out, int n) {
    int i = blockIdx.x * blockDim.x + threadIdx.x;
    if (i >= n) return;
    int beg = row_start[i], end = row_start[i + 1];
    float s0 = 0.f, s1 = 0.f, s2 = 0.f, s3 = 0.f;
    int e = beg;
    for (; e + 4 <= end; e += 4) {
        s0 += z[csr_src[e + 0]];
        s1 += z[csr_src[e + 1]];
        s2 += z[csr_src[e + 2]];
        s3 += z[csr_src[e + 3]];
    }
    for (; e < end; ++e) s0 += z[csr_src[e]];
    float v = fmaf(dis[i], z[i] + ((s0 + s1) + (s2 + s3)), c0[0]);
    out[i] = 1.f / (1.f + expf(-v));
}

// ---------------- fallback kernels (only if ws too small / shape odd) --------

__global__ void relu_k(float* __restrict__ p, long long m) {
    long long i = (long long)blockIdx.x * blockDim.x + threadIdx.x;
    if (i < m) p[i] = fmaxf(p[i], 0.f);
}
__global__ void deg_init_k(float* __restrict__ deg, int n) {
    int i = blockIdx.x * blockDim.x + threadIdx.x;
    if (i < n) deg[i] = 1.0f;
}
__global__ void deg_edges_k(const int* __restrict__ dst, float* __restrict__ deg, int E) {
    int e = blockIdx.x * blockDim.x + threadIdx.x;
    if (e < E) atomicAdd(&deg[dst[e]], 1.0f);
}
__global__ void dis_k(float* __restrict__ deg, int n) {
    int i = blockIdx.x * blockDim.x + threadIdx.x;
    if (i < n) deg[i] = rsqrtf(deg[i]);
}
__global__ void init_agg_k(const float* __restrict__ t, const float* __restrict__ dis,
                           const float* __restrict__ b, float* __restrict__ agg, int n) {
    int idx = blockIdx.x * blockDim.x + threadIdx.x;
    if (idx >= n * 64) return;
    int i = idx >> 6, jj = idx & 63;
    float ds = dis[i];
    agg[idx] = ds * ds * t[idx] + b[jj];
}
__global__ __launch_bounds__(256) void agg_edges_k(
    const int* __restrict__ src, const int* __restrict__ dst,
    const float* __restrict__ dis, const float* __restrict__ t,
    float* __restrict__ agg, int E) {
    int e    = (int)((blockIdx.x * blockDim.x + threadIdx.x) >> 6);
    int lane = threadIdx.x & 63;
    if (e >= E) return;
    int s = src[e], d = dst[e];
    float w = dis[s] * dis[d];
    atomicAdd(&agg[(size_t)d * 64 + lane], w * t[(size_t)s * 64 + lane]);
}
__global__ __launch_bounds__(256) void final_k(
    const float* __restrict__ agg, const float* __restrict__ Wl,
    const float* __restrict__ bl, float* __restrict__ out, int n) {
    int node = (int)((blockIdx.x * blockDim.x + threadIdx.x) >> 6);
    int lane = threadIdx.x & 63;
    if (node >= n) return;
    float v = agg[(size_t)node * 64 + lane] * Wl[lane];
    #pragma unroll
    for (int m = 32; m >= 1; m >>= 1) v += __shfl_xor(v, m);
    if (lane == 0) out[node] = 1.f / (1.f + expf(-(v + bl[0])));
}
template <int K>
__global__ __launch_bounds__(256) void gemm_rows4_k(
    const float* __restrict__ X, const float* __restrict__ W,
    float* __restrict__ Y, int n) {
    __shared__ float Ws[K * 64];
    for (int t = threadIdx.x; t < K * 64; t += blockDim.x) Ws[t] = W[t];
    __syncthreads();
    int wave   = (int)((blockIdx.x * blockDim.x + threadIdx.x) >> 6);
    int lane   = threadIdx.x & 63;
    int nwaves = (int)((gridDim.x * blockDim.x) >> 6);
    for (int r = wave; r < n; r += nwaves) {
        const float* xr = X + (size_t)r * K;
        float acc = 0.f;
        for (int k = 0; k < K; k += 4) {
            float4 a = *reinterpret_cast<const float4*>(xr + k);
            acc = fmaf(a.x, Ws[(k + 0) * 64 + lane], acc);
            acc = fmaf(a.y, Ws[(k + 1) * 64 + lane], acc);
            acc = fmaf(a.z, Ws[(k + 2) * 64 + lane], acc);
            acc = fmaf(a.w, Ws[(k + 3) * 64 + lane], acc);
        }
        Y[(size_t)r * 64 + lane] = acc;
    }
}

// ---------------------------------------------------------------------------

extern "C" void kernel_launch(void* const* d_in, const int* in_sizes, int n_in,
                              void* d_out, int out_size, void* d_ws, size_t ws_size,
                              hipStream_t stream) {
    const float* x  = (const float*)d_in[0];
    const int*   ei = (const int*)d_in[1];
    const float* W1 = (const float*)d_in[2];
    const float* b1 = (const float*)d_in[3];
    const float* W2 = (const float*)d_in[4];
    const float* b2 = (const float*)d_in[5];
    const float* Wl = (const float*)d_in[6];
    const float* bl = (const float*)d_in[7];
    float* out = (float*)d_out;

    const int n = in_sizes[0] / 128;      // 100000
    const int E = in_sizes[1] / 2;        // 1600000
    const int* src = ei;
    const int* dst = ei + E;

    const int B = 256;
    dim3 blk(B);
    auto align512 = [](size_t v) { return (v + 511) & ~(size_t)511; };

    // workspace layout
    char* ws = (char*)d_ws;
    size_t off = 0;
    float*          dis     = (float*)(ws + off); off = align512(off + (size_t)n * 4);
    int*            row_st  = (int*)  (ws + off); off = align512(off + (size_t)(n + 1) * 4);
    int*            bcnt    = (int*)  (ws + off); off = align512(off + (size_t)(NBMAX + 1) * 4);
    int*            bbase   = (int*)  (ws + off); off = align512(off + (size_t)(NBMAX + 1) * 4);
    int*            bcur    = (int*)  (ws + off); off = align512(off + (size_t)NBMAX * 4);
    float*          c0      = (float*)(ws + off); off = align512(off + 512);
    float*          w2l     = (float*)(ws + off); off = align512(off + 64 * 4);
    float*          zbuf    = (float*)(ws + off); off = align512(off + (size_t)n * 4);
    int*            csr_src = (int*)  (ws + off); off = align512(off + (size_t)E * 4);
    unsigned short* bufA16  = (unsigned short*)(ws + off); off = align512(off + (size_t)n * 64 * 2);
    int*            stage   = (int*)  (ws + off); off = align512(off + (size_t)E * 4);
    unsigned short* fw1     = (unsigned short*)(ws + off); off = align512(off + 8192 * 2);
    size_t need_csr = off;

    const int nbuckets = (n + 255) >> 8;
    const int nebl = (E + EPB - 1) / EPB;   // edge blocks

    if (ws_size >= need_csr && (n & 15) == 0 && nbuckets <= NBMAX && n <= (1 << 17)) {
        // ---- W1 frag pack + w2l + c0 + bcnt zero (one small launch) ----
        wfrag_k<<<48, blk, 0, stream>>>(W1, W2, fw1, w2l, b2, Wl, bl, c0, bcnt);

        // ---- CSR build (LDS-privatized; node lists src-tile-ordered) ----
        bcount_k<<<nebl, blk, 0, stream>>>(dst, bcnt, E, nbuckets);
        bscan_k<<<1, 512, 0, stream>>>(bcnt, bbase, bcur, nbuckets);
        partition_k<<<nebl, blk, 0, stream>>>(src, dst, bcur, stage, E, nbuckets);
        bucket_place_k<<<nbuckets, blk, 0, stream>>>(stage, bbase, row_st, dis, csr_src, n, nbuckets);

        int gemm_blocks = ((n >> 4) + 3) / 4;   // one wave per 16-row tile

        // ---- layer 1 GEMM: bufA16 = bf16(dis * (x @ W1)) ----
        mfma_gemm_k<128><<<gemm_blocks, blk, 0, stream>>>(x, fw1, dis, bufA16, n);

        // ---- fused gather1 + relu + (W2@Wl) dot -> z ----
        gather_k<<<((size_t)n * 64 + B - 1) / B, blk, 0, stream>>>(
            row_st, csr_src, dis, bufA16, b1, w2l, zbuf, n);

        // ---- layer-2 scalar aggregation + sigmoid ----
        gatherz_k<<<(n + B - 1) / B, blk, 0, stream>>>(
            row_st, csr_src, dis, zbuf, c0, out, n);
    } else {
        // ---- fallback: atomic scatter, fp32 GEMM ----
        size_t o2 = 0;
        float* dis2 = (float*)(ws + o2); o2 = align512(o2 + (size_t)n * 4);
        float* bA   = (float*)(ws + o2); o2 += (size_t)n * 64 * 4;
        float* bB   = (float*)(ws + o2);

        deg_init_k<<<(n + B - 1) / B, blk, 0, stream>>>(dis2, n);
        deg_edges_k<<<(E + B - 1) / B, blk, 0, stream>>>(dst, dis2, E);
        dis_k<<<(n + B - 1) / B, blk, 0, stream>>>(dis2, n);

        gemm_rows4_k<128><<<2048, blk, 0, stream>>>(x, W1, bA, n);
        init_agg_k<<<((size_t)n * 64 + B - 1) / B, blk, 0, stream>>>(bA, dis2, b1, bB, n);
        agg_edges_k<<<(E + 3) / 4, blk, 0, stream>>>(src, dst, dis2, bA, bB, E);
        relu_k<<<((size_t)n * 64 + B - 1) / B, blk, 0, stream>>>(bB, (long long)n * 64);

        gemm_rows4_k<64><<<2048, blk, 0, stream>>>(bB, W2, bA, n);
        init_agg_k<<<((size_t)n * 64 + B - 1) / B, blk, 0, stream>>>(bA, dis2, b2, bB, n);
        agg_edges_k<<<(E + 3) / 4, blk, 0, stream>>>(src, dst, dis2, bA, bB, E);

        final_k<<<(n + 3) / 4, blk, 0, stream>>>(bB, Wl, bl, out, n);
    }
}

// Round 14
// 122.187 us; speedup vs baseline: 1.7568x; 1.0822x over previous
//
#include <hip/hip_runtime.h>
#include <hip/hip_bf16.h>

// ---------------------------------------------------------------------------
// EnhancedGNN: 2-layer GCN + linear head + sigmoid.
// R14: CSR build streamlined to 2 kernels — partition writes fixed-capacity
//      bins (CAP = mean+16sigma, no pre-count/pre-scan), bucket_place computes
//      its own CSR base from bucket counts (no bscan). 9 -> 6 dispatches.
//      Gather: 16-deep load batching (same 64-lane row-contiguous shape).
//      Algebraic folds as R11: z in gather epilogue via w2l=W2@Wl; gemm2 gone;
//      head folded into scalar gatherz.
// ---------------------------------------------------------------------------

#define EPB 4096      // edges per partition block
#define NBMAX 512     // max buckets (n/256) handled by the fast path

typedef __attribute__((ext_vector_type(8))) short bf16x8;
typedef __attribute__((ext_vector_type(4))) float f32x4;

__device__ __forceinline__ unsigned short f2b(float f) {   // fp32->bf16 RNE
    unsigned u = __builtin_bit_cast(unsigned, f);
    u += 0x7fffu + ((u >> 16) & 1u);
    return (unsigned short)(u >> 16);
}
__device__ __forceinline__ float b2f(unsigned short h) {
    unsigned u = (unsigned)h << 16;
    return __builtin_bit_cast(float, u);
}

// ---------------- CSR build (2 kernels) ----------------

// Partition edges into fixed-capacity dst-bucket bins. Packed: src | dstLow<<17.
// bucket_cur starts at 0 (zeroed by wfrag) -> ends holding per-bucket counts.
__global__ __launch_bounds__(256) void partition_k(
    const int* __restrict__ src, const int* __restrict__ dst,
    int* __restrict__ bucket_cur, int* __restrict__ stage,
    int E, int nbuckets, int cap) {
    __shared__ int ls[EPB];
    __shared__ int ld[EPB];
    __shared__ int lhist[NBMAX];
    __shared__ int lbase[NBMAX];
    int e0 = blockIdx.x * EPB;
    int cnt = min(EPB, E - e0);
    int t = threadIdx.x;
    for (int i = t; i < cnt; i += 256) { ls[i] = src[e0 + i]; ld[i] = dst[e0 + i]; }
    for (int b = t; b < nbuckets; b += 256) lhist[b] = 0;
    __syncthreads();
    for (int i = t; i < cnt; i += 256) atomicAdd(&lhist[ld[i] >> 8], 1);
    __syncthreads();
    for (int b = t; b < nbuckets; b += 256) {
        int c = lhist[b];
        lbase[b] = (c > 0) ? atomicAdd(&bucket_cur[b], c) : 0;
        lhist[b] = 0;
    }
    __syncthreads();
    for (int i = t; i < cnt; i += 256) {
        int d  = ld[i];
        int b  = d >> 8;
        int off = atomicAdd(&lhist[b], 1);
        stage[(size_t)b * cap + lbase[b] + off] = ls[i] | ((d & 255) << 17);
    }
}

// One block per bucket: compute own CSR base (prefix of bucket counts), then
// per-node LDS hist + scan -> row_start, dis, and csr placement.
__global__ __launch_bounds__(256) void bucket_place_k(
    const int* __restrict__ stage, const int* __restrict__ bucket_cnt,
    int* __restrict__ row_start, float* __restrict__ dis,
    int* __restrict__ csr_src, int n, int nbuckets, int cap) {
    __shared__ int red[256];
    __shared__ int lh[256];
    __shared__ int ss[256];
    __shared__ int lcur[256];
    int b = blockIdx.x;
    int t = threadIdx.x;
    int total = bucket_cnt[b];

    // base = sum of bucket_cnt[0..b)
    int partial = 0;
    for (int i = t; i < b; i += 256) partial += bucket_cnt[i];
    red[t] = partial; __syncthreads();
    #pragma unroll
    for (int m = 128; m > 0; m >>= 1) {
        if (t < m) red[t] += red[t + m];
        __syncthreads();
    }
    int base = red[0];

    // per-node histogram over this bucket's bin
    lh[t] = 0;
    __syncthreads();
    size_t ebeg = (size_t)b * cap;
    size_t eend = ebeg + total;
    for (size_t e = ebeg + t; e < eend; e += 256)
        atomicAdd(&lh[(stage[e] >> 17) & 255], 1);
    __syncthreads();

    int cnt = lh[t];
    ss[t] = cnt;
    __syncthreads();
    #pragma unroll
    for (int off = 1; off < 256; off <<= 1) {
        int u = (t >= off) ? ss[t - off] : 0;
        __syncthreads();
        ss[t] += u;
        __syncthreads();
    }
    int excl = ss[t] - cnt;
    int node = (b << 8) + t;
    if (node < n) {
        row_start[node] = base + excl;
        dis[node] = rsqrtf((float)cnt + 1.0f);
    }
    lcur[t] = base + excl;
    if (b == nbuckets - 1 && t == 0) row_start[n] = base + total;   // = E
    __syncthreads();

    for (size_t e = ebeg + t; e < eend; e += 256) {
        int p = stage[e];
        int pos = atomicAdd(&lcur[(p >> 17) & 255], 1);
        csr_src[pos] = p & 0x1FFFF;
    }
}

// ---------------- W1 frag pack + w2l + c0 + bucket_cur zero ------------------
__global__ void wfrag_k(const float* __restrict__ W1, const float* __restrict__ W2,
                        unsigned short* __restrict__ fw1, float* __restrict__ w2l,
                        const float* __restrict__ b2, const float* __restrict__ Wl,
                        const float* __restrict__ bl, float* __restrict__ c0,
                        int* __restrict__ bcur) {
    int gid = blockIdx.x * blockDim.x + threadIdx.x;
    if (gid < NBMAX) bcur[gid] = 0;                        // zero bucket counters
    if (blockIdx.x == 0 && threadIdx.x < 64) {             // c0 = dot(b2,Wl)+bl
        float v = b2[threadIdx.x] * Wl[threadIdx.x];
        #pragma unroll
        for (int m = 32; m >= 1; m >>= 1) v += __shfl_xor(v, m);
        if (threadIdx.x == 0) c0[0] = v + bl[0];
    }
    if (blockIdx.x == 1 && threadIdx.x < 64) {             // w2l = W2 @ Wl
        int k = threadIdx.x;
        float s = 0.f;
        #pragma unroll 8
        for (int j = 0; j < 64; ++j) s = fmaf(W2[k * 64 + j], Wl[j], s);
        w2l[k] = s;
    }
    if (gid < 8192) {                                      // W1 B-fragments
        int f = gid >> 9, rem = gid & 511;
        int l = rem >> 3, i = rem & 7;
        int ks = f >> 2, ct = f & 3;
        int k = ks * 32 + ((l >> 4) << 3) + i;
        int c = ct * 16 + (l & 15);
        fw1[gid] = f2b(W1[k * 64 + c]);
    }
}

// ---------------- MFMA GEMM1: Y[r,:] = bf16( dis[r] * (x[r,:] @ W1) ) --------
template <int K>
__global__ __launch_bounds__(256) void mfma_gemm_k(
    const float* __restrict__ X, const unsigned short* __restrict__ FW,
    const float* __restrict__ dis, unsigned short* __restrict__ Y, int n) {
    constexpr int KS = K / 32;
    int wave   = (int)((blockIdx.x * blockDim.x + threadIdx.x) >> 6);
    int lane   = threadIdx.x & 63;
    int nwaves = (int)((gridDim.x * blockDim.x) >> 6);
    int ntiles = n >> 4;

    bf16x8 bfrag[KS][4];
    #pragma unroll
    for (int ks = 0; ks < KS; ++ks)
        #pragma unroll
        for (int ct = 0; ct < 4; ++ct)
            bfrag[ks][ct] = *reinterpret_cast<const bf16x8*>(FW + ((ks * 4 + ct) << 9) + (lane << 3));

    int rb = lane & 15;
    int kb = (lane >> 4) << 3;

    for (int tile = wave; tile < ntiles; tile += nwaves) {
        int row = (tile << 4) + rb;
        f32x4 acc[4];
        #pragma unroll
        for (int ct = 0; ct < 4; ++ct) acc[ct] = (f32x4){0.f, 0.f, 0.f, 0.f};

        #pragma unroll
        for (int ks = 0; ks < KS; ++ks) {
            const float* p = X + (size_t)row * K + ks * 32 + kb;
            float4 u = *reinterpret_cast<const float4*>(p);
            float4 v = *reinterpret_cast<const float4*>(p + 4);
            bf16x8 af;
            af[0] = (short)f2b(u.x); af[1] = (short)f2b(u.y);
            af[2] = (short)f2b(u.z); af[3] = (short)f2b(u.w);
            af[4] = (short)f2b(v.x); af[5] = (short)f2b(v.y);
            af[6] = (short)f2b(v.z); af[7] = (short)f2b(v.w);
            #pragma unroll
            for (int ct = 0; ct < 4; ++ct)
                acc[ct] = __builtin_amdgcn_mfma_f32_16x16x32_bf16(af, bfrag[ks][ct], acc[ct], 0, 0, 0);
        }

        int orow0 = (tile << 4) + ((lane >> 4) << 2);
        int ocol  = lane & 15;
        float dv0 = dis[orow0], dv1 = dis[orow0 + 1], dv2 = dis[orow0 + 2], dv3 = dis[orow0 + 3];
        #pragma unroll
        for (int ct = 0; ct < 4; ++ct) {
            Y[(size_t)(orow0 + 0) * 64 + ct * 16 + ocol] = f2b(acc[ct][0] * dv0);
            Y[(size_t)(orow0 + 1) * 64 + ct * 16 + ocol] = f2b(acc[ct][1] * dv1);
            Y[(size_t)(orow0 + 2) * 64 + ct * 16 + ocol] = f2b(acc[ct][2] * dv2);
            Y[(size_t)(orow0 + 3) * 64 + ct * 16 + ocol] = f2b(acc[ct][3] * dv3);
        }
    }
}

// ---------------- fused gather1 + (relu, W2@Wl dot) -> z ---------------------
// Per node: agg = tp[node] + sum_{s in N} tp[s]  (tp rows pre-scaled by dis);
// h1 = relu(dd*agg + b1) in registers; z[node] = dd * dot(h1, w2l).
// 16-deep load batching inside the 64-edge shfl window.
__global__ __launch_bounds__(256) void gather_k(
    const int* __restrict__ row_start, const int* __restrict__ csr_src,
    const float* __restrict__ dis, const unsigned short* __restrict__ tp,
    const float* __restrict__ b, const float* __restrict__ w2l,
    float* __restrict__ z, int n) {
    int node = (int)((blockIdx.x * blockDim.x + threadIdx.x) >> 6);
    int lane = threadIdx.x & 63;
    if (node >= n) return;
    int beg = row_start[node], end = row_start[node + 1];
    float dd = dis[node];
    float a0 = b2f(tp[(size_t)node * 64 + lane]);   // self term (pre-scaled)
    float a1 = 0.f, a2 = 0.f, a3 = 0.f, a4 = 0.f, a5 = 0.f, a6 = 0.f, a7 = 0.f;

    for (int base = beg; base < end; base += 64) {
        int rem = end - base;
        int cnt = rem < 64 ? rem : 64;
        int idx = (lane < cnt) ? csr_src[base + lane] : 0;   // coalesced window
        int j = 0;
        for (; j + 16 <= cnt; j += 16) {                      // 16 loads in flight
            int   sarr[16];
            float varr[16];
            #pragma unroll
            for (int k = 0; k < 16; ++k) sarr[k] = __shfl(idx, j + k);
            #pragma unroll
            for (int k = 0; k < 16; ++k) varr[k] = b2f(tp[(size_t)sarr[k] * 64 + lane]);
            a0 += varr[0];  a1 += varr[1];  a2 += varr[2];  a3 += varr[3];
            a4 += varr[4];  a5 += varr[5];  a6 += varr[6];  a7 += varr[7];
            a0 += varr[8];  a1 += varr[9];  a2 += varr[10]; a3 += varr[11];
            a4 += varr[12]; a5 += varr[13]; a6 += varr[14]; a7 += varr[15];
        }
        if (j + 8 <= cnt) {
            int s0 = __shfl(idx, j + 0), s1 = __shfl(idx, j + 1);
            int s2 = __shfl(idx, j + 2), s3 = __shfl(idx, j + 3);
            int s4 = __shfl(idx, j + 4), s5 = __shfl(idx, j + 5);
            int s6 = __shfl(idx, j + 6), s7 = __shfl(idx, j + 7);
            a0 += b2f(tp[(size_t)s0 * 64 + lane]);
            a1 += b2f(tp[(size_t)s1 * 64 + lane]);
            a2 += b2f(tp[(size_t)s2 * 64 + lane]);
            a3 += b2f(tp[(size_t)s3 * 64 + lane]);
            a4 += b2f(tp[(size_t)s4 * 64 + lane]);
            a5 += b2f(tp[(size_t)s5 * 64 + lane]);
            a6 += b2f(tp[(size_t)s6 * 64 + lane]);
            a7 += b2f(tp[(size_t)s7 * 64 + lane]);
            j += 8;
        }
        if (j + 4 <= cnt) {
            int s0 = __shfl(idx, j + 0), s1 = __shfl(idx, j + 1);
            int s2 = __shfl(idx, j + 2), s3 = __shfl(idx, j + 3);
            a0 += b2f(tp[(size_t)s0 * 64 + lane]);
            a1 += b2f(tp[(size_t)s1 * 64 + lane]);
            a2 += b2f(tp[(size_t)s2 * 64 + lane]);
            a3 += b2f(tp[(size_t)s3 * 64 + lane]);
            j += 4;
        }
        for (; j < cnt; ++j) {
            int s = __shfl(idx, j);
            a4 += b2f(tp[(size_t)s * 64 + lane]);
        }
    }

    float acc = ((a0 + a1) + (a2 + a3)) + ((a4 + a5) + (a6 + a7));
    float h = fmaxf(fmaf(dd, acc, b[lane]), 0.f);   // h1[node][lane], fp32
    float v = h * w2l[lane];
    #pragma unroll
    for (int m = 32; m >= 1; m >>= 1) v += __shfl_xor(v, m);
    if (lane == 0) z[node] = dd * v;
}

// ---------------- layer-2 scalar gather + sigmoid (head folded) -------------
__global__ __launch_bounds__(256) void gatherz_k(
    const int* __restrict__ row_start, const int* __restrict__ csr_src,
    const float* __restrict__ dis, const float* __restrict__ z,
    const float* __restrict__ c0, float* __restrict__ out, int n) {
    int i = blockIdx.x * blockDim.x + threadIdx.x;
    if (i >= n) return;
    int beg = row_start[i], end = row_start[i + 1];
    float s0 = 0.f, s1 = 0.f, s2 = 0.f, s3 = 0.f;
    int e = beg;
    for (; e + 4 <= end; e += 4) {
        s0 += z[csr_src[e + 0]];
        s1 += z[csr_src[e + 1]];
        s2 += z[csr_src[e + 2]];
        s3 += z[csr_src[e + 3]];
    }
    for (; e < end; ++e) s0 += z[csr_src[e]];
    float v = fmaf(dis[i], z[i] + ((s0 + s1) + (s2 + s3)), c0[0]);
    out[i] = 1.f / (1.f + expf(-v));
}

// ---------------- fallback kernels (only if ws too small / shape odd) --------

__global__ void relu_k(float* __restrict__ p, long long m) {
    long long i = (long long)blockIdx.x * blockDim.x + threadIdx.x;
    if (i < m) p[i] = fmaxf(p[i], 0.f);
}
__global__ void deg_init_k(float* __restrict__ deg, int n) {
    int i = blockIdx.x * blockDim.x + threadIdx.x;
    if (i < n) deg[i] = 1.0f;
}
__global__ void deg_edges_k(const int* __restrict__ dst, float* __restrict__ deg, int E) {
    int e = blockIdx.x * blockDim.x + threadIdx.x;
    if (e < E) atomicAdd(&deg[dst[e]], 1.0f);
}
__global__ void dis_k(float* __restrict__ deg, int n) {
    int i = blockIdx.x * blockDim.x + threadIdx.x;
    if (i < n) deg[i] = rsqrtf(deg[i]);
}
__global__ void init_agg_k(const float* __restrict__ t, const float* __restrict__ dis,
                           const float* __restrict__ b, float* __restrict__ agg, int n) {
    int idx = blockIdx.x * blockDim.x + threadIdx.x;
    if (idx >= n * 64) return;
    int i = idx >> 6, jj = idx & 63;
    float ds = dis[i];
    agg[idx] = ds * ds * t[idx] + b[jj];
}
__global__ __launch_bounds__(256) void agg_edges_k(
    const int* __restrict__ src, const int* __restrict__ dst,
    const float* __restrict__ dis, const float* __restrict__ t,
    float* __restrict__ agg, int E) {
    int e    = (int)((blockIdx.x * blockDim.x + threadIdx.x) >> 6);
    int lane = threadIdx.x & 63;
    if (e >= E) return;
    int s = src[e], d = dst[e];
    float w = dis[s] * dis[d];
    atomicAdd(&agg[(size_t)d * 64 + lane], w * t[(size_t)s * 64 + lane]);
}
__global__ __launch_bounds__(256) void final_k(
    const float* __restrict__ agg, const float* __restrict__ Wl,
    const float* __restrict__ bl, float* __restrict__ out, int n) {
    int node = (int)((blockIdx.x * blockDim.x + threadIdx.x) >> 6);
    int lane = threadIdx.x & 63;
    if (node >= n) return;
    float v = agg[(size_t)node * 64 + lane] * Wl[lane];
    #pragma unroll
    for (int m = 32; m >= 1; m >>= 1) v += __shfl_xor(v, m);
    if (lane == 0) out[node] = 1.f / (1.f + expf(-(v + bl[0])));
}
template <int K>
__global__ __launch_bounds__(256) void gemm_rows4_k(
    const float* __restrict__ X, const float* __restrict__ W,
    float* __restrict__ Y, int n) {
    __shared__ float Ws[K * 64];
    for (int t = threadIdx.x; t < K * 64; t += blockDim.x) Ws[t] = W[t];
    __syncthreads();
    int wave   = (int)((blockIdx.x * blockDim.x + threadIdx.x) >> 6);
    int lane   = threadIdx.x & 63;
    int nwaves = (int)((gridDim.x * blockDim.x) >> 6);
    for (int r = wave; r < n; r += nwaves) {
        const float* xr = X + (size_t)r * K;
        float acc = 0.f;
        for (int k = 0; k < K; k += 4) {
            float4 a = *reinterpret_cast<const float4*>(xr + k);
            acc = fmaf(a.x, Ws[(k + 0) * 64 + lane], acc);
            acc = fmaf(a.y, Ws[(k + 1) * 64 + lane], acc);
            acc = fmaf(a.z, Ws[(k + 2) * 64 + lane], acc);
            acc = fmaf(a.w, Ws[(k + 3) * 64 + lane], acc);
        }
        Y[(size_t)r * 64 + lane] = acc;
    }
}

// ---------------------------------------------------------------------------

extern "C" void kernel_launch(void* const* d_in, const int* in_sizes, int n_in,
                              void* d_out, int out_size, void* d_ws, size_t ws_size,
                              hipStream_t stream) {
    const float* x  = (const float*)d_in[0];
    const int*   ei = (const int*)d_in[1];
    const float* W1 = (const float*)d_in[2];
    const float* b1 = (const float*)d_in[3];
    const float* W2 = (const float*)d_in[4];
    const float* b2 = (const float*)d_in[5];
    const float* Wl = (const float*)d_in[6];
    const float* bl = (const float*)d_in[7];
    float* out = (float*)d_out;

    const int n = in_sizes[0] / 128;      // 100000
    const int E = in_sizes[1] / 2;        // 1600000
    const int* src = ei;
    const int* dst = ei + E;

    const int B = 256;
    dim3 blk(B);
    auto align512 = [](size_t v) { return (v + 511) & ~(size_t)511; };

    const int nbuckets = (n + 255) >> 8;
    // bin capacity: mean + ~16 sigma for Poisson bucket loads, 64-aligned
    const int CAP = nbuckets > 0 ? (((E / nbuckets) + 1024 + 63) & ~63) : 0;

    // workspace layout
    char* ws = (char*)d_ws;
    size_t off = 0;
    float*          dis     = (float*)(ws + off); off = align512(off + (size_t)n * 4);
    int*            row_st  = (int*)  (ws + off); off = align512(off + (size_t)(n + 1) * 4);
    int*            bcur    = (int*)  (ws + off); off = align512(off + (size_t)NBMAX * 4);
    float*          c0      = (float*)(ws + off); off = align512(off + 512);
    float*          w2l     = (float*)(ws + off); off = align512(off + 64 * 4);
    float*          zbuf    = (float*)(ws + off); off = align512(off + (size_t)n * 4);
    int*            csr_src = (int*)  (ws + off); off = align512(off + (size_t)E * 4);
    unsigned short* bufA16  = (unsigned short*)(ws + off); off = align512(off + (size_t)n * 64 * 2);
    int*            stage   = (int*)  (ws + off); off = align512(off + (size_t)nbuckets * CAP * 4);
    unsigned short* fw1     = (unsigned short*)(ws + off); off = align512(off + 8192 * 2);
    size_t need_csr = off;

    const int nebl = (E + EPB - 1) / EPB;   // edge blocks

    if (ws_size >= need_csr && (n & 15) == 0 && nbuckets <= NBMAX && n <= (1 << 17)) {
        // ---- W1 frag pack + w2l + c0 + bucket_cur zero (one small launch) ----
        wfrag_k<<<48, blk, 0, stream>>>(W1, W2, fw1, w2l, b2, Wl, bl, c0, bcur);

        // ---- CSR build: bins -> (row_start, dis, csr) ----
        partition_k<<<nebl, blk, 0, stream>>>(src, dst, bcur, stage, E, nbuckets, CAP);
        bucket_place_k<<<nbuckets, blk, 0, stream>>>(stage, bcur, row_st, dis, csr_src, n, nbuckets, CAP);

        int gemm_blocks = ((n >> 4) + 3) / 4;   // one wave per 16-row tile

        // ---- layer 1 GEMM: bufA16 = bf16(dis * (x @ W1)) ----
        mfma_gemm_k<128><<<gemm_blocks, blk, 0, stream>>>(x, fw1, dis, bufA16, n);

        // ---- fused gather1 + relu + (W2@Wl) dot -> z ----
        gather_k<<<((size_t)n * 64 + B - 1) / B, blk, 0, stream>>>(
            row_st, csr_src, dis, bufA16, b1, w2l, zbuf, n);

        // ---- layer-2 scalar aggregation + sigmoid ----
        gatherz_k<<<(n + B - 1) / B, blk, 0, stream>>>(
            row_st, csr_src, dis, zbuf, c0, out, n);
    } else {
        // ---- fallback: atomic scatter, fp32 GEMM ----
        size_t o2 = 0;
        float* dis2 = (float*)(ws + o2); o2 = align512(o2 + (size_t)n * 4);
        float* bA   = (float*)(ws + o2); o2 += (size_t)n * 64 * 4;
        float* bB   = (float*)(ws + o2);

        deg_init_k<<<(n + B - 1) / B, blk, 0, stream>>>(dis2, n);
        deg_edges_k<<<(E + B - 1) / B, blk, 0, stream>>>(dst, dis2, E);
        dis_k<<<(n + B - 1) / B, blk, 0, stream>>>(dis2, n);

        gemm_rows4_k<128><<<2048, blk, 0, stream>>>(x, W1, bA, n);
        init_agg_k<<<((size_t)n * 64 + B - 1) / B, blk, 0, stream>>>(bA, dis2, b1, bB, n);
        agg_edges_k<<<(E + 3) / 4, blk, 0, stream>>>(src, dst, dis2, bA, bB, E);
        relu_k<<<((size_t)n * 64 + B - 1) / B, blk, 0, stream>>>(bB, (long long)n * 64);

        gemm_rows4_k<64><<<2048, blk, 0, stream>>>(bB, W2, bA, n);
        init_agg_k<<<((size_t)n * 64 + B - 1) / B, blk, 0, stream>>>(bA, dis2, b2, bB, n);
        agg_edges_k<<<(E + 3) / 4, blk, 0, stream>>>(src, dst, dis2, bA, bB, E);

        final_k<<<(n + 3) / 4, blk, 0, stream>>>(bB, Wl, bl, out, n);
    }
}

// Round 15
// 118.149 us; speedup vs baseline: 1.8169x; 1.0342x over previous
//
#include <hip/hip_runtime.h>
#include <hip/hip_bf16.h>

// ---------------------------------------------------------------------------
// EnhancedGNN: 2-layer GCN + linear head + sigmoid.
// R15: R14's 2-kernel CSR build (fixed-capacity bins, self-computed base)
//      + gather reverted to the proven R11 8-deep / VGPR-24 shape (R14's
//      16-deep batching cost occupancy: 51 -> 55us; reverted).
//      Algebraic folds: z = dd*dot(relu(agg1+b1), W2@Wl) in gather epilogue;
//      gemm2 eliminated; head folded into scalar gatherz. bf16 features,
//      dis pre-scaled at gemm1 store.
// ---------------------------------------------------------------------------

#define EPB 4096      // edges per partition block
#define NBMAX 512     // max buckets (n/256) handled by the fast path

typedef __attribute__((ext_vector_type(8))) short bf16x8;
typedef __attribute__((ext_vector_type(4))) float f32x4;

__device__ __forceinline__ unsigned short f2b(float f) {   // fp32->bf16 RNE
    unsigned u = __builtin_bit_cast(unsigned, f);
    u += 0x7fffu + ((u >> 16) & 1u);
    return (unsigned short)(u >> 16);
}
__device__ __forceinline__ float b2f(unsigned short h) {
    unsigned u = (unsigned)h << 16;
    return __builtin_bit_cast(float, u);
}

// ---------------- CSR build (2 kernels) ----------------

// Partition edges into fixed-capacity dst-bucket bins. Packed: src | dstLow<<17.
// bucket_cur starts at 0 (zeroed by wfrag) -> ends holding per-bucket counts.
__global__ __launch_bounds__(256) void partition_k(
    const int* __restrict__ src, const int* __restrict__ dst,
    int* __restrict__ bucket_cur, int* __restrict__ stage,
    int E, int nbuckets, int cap) {
    __shared__ int ls[EPB];
    __shared__ int ld[EPB];
    __shared__ int lhist[NBMAX];
    __shared__ int lbase[NBMAX];
    int e0 = blockIdx.x * EPB;
    int cnt = min(EPB, E - e0);
    int t = threadIdx.x;
    for (int i = t; i < cnt; i += 256) { ls[i] = src[e0 + i]; ld[i] = dst[e0 + i]; }
    for (int b = t; b < nbuckets; b += 256) lhist[b] = 0;
    __syncthreads();
    for (int i = t; i < cnt; i += 256) atomicAdd(&lhist[ld[i] >> 8], 1);
    __syncthreads();
    for (int b = t; b < nbuckets; b += 256) {
        int c = lhist[b];
        lbase[b] = (c > 0) ? atomicAdd(&bucket_cur[b], c) : 0;
        lhist[b] = 0;
    }
    __syncthreads();
    for (int i = t; i < cnt; i += 256) {
        int d  = ld[i];
        int b  = d >> 8;
        int off = atomicAdd(&lhist[b], 1);
        stage[(size_t)b * cap + lbase[b] + off] = ls[i] | ((d & 255) << 17);
    }
}

// One block per bucket: compute own CSR base (prefix of bucket counts), then
// per-node LDS hist + scan -> row_start, dis, and csr placement.
__global__ __launch_bounds__(256) void bucket_place_k(
    const int* __restrict__ stage, const int* __restrict__ bucket_cnt,
    int* __restrict__ row_start, float* __restrict__ dis,
    int* __restrict__ csr_src, int n, int nbuckets, int cap) {
    __shared__ int red[256];
    __shared__ int lh[256];
    __shared__ int ss[256];
    __shared__ int lcur[256];
    int b = blockIdx.x;
    int t = threadIdx.x;
    int total = bucket_cnt[b];

    // base = sum of bucket_cnt[0..b)
    int partial = 0;
    for (int i = t; i < b; i += 256) partial += bucket_cnt[i];
    red[t] = partial; __syncthreads();
    #pragma unroll
    for (int m = 128; m > 0; m >>= 1) {
        if (t < m) red[t] += red[t + m];
        __syncthreads();
    }
    int base = red[0];

    // per-node histogram over this bucket's bin
    lh[t] = 0;
    __syncthreads();
    size_t ebeg = (size_t)b * cap;
    size_t eend = ebeg + total;
    for (size_t e = ebeg + t; e < eend; e += 256)
        atomicAdd(&lh[(stage[e] >> 17) & 255], 1);
    __syncthreads();

    int cnt = lh[t];
    ss[t] = cnt;
    __syncthreads();
    #pragma unroll
    for (int off = 1; off < 256; off <<= 1) {
        int u = (t >= off) ? ss[t - off] : 0;
        __syncthreads();
        ss[t] += u;
        __syncthreads();
    }
    int excl = ss[t] - cnt;
    int node = (b << 8) + t;
    if (node < n) {
        row_start[node] = base + excl;
        dis[node] = rsqrtf((float)cnt + 1.0f);
    }
    lcur[t] = base + excl;
    if (b == nbuckets - 1 && t == 0) row_start[n] = base + total;   // = E
    __syncthreads();

    for (size_t e = ebeg + t; e < eend; e += 256) {
        int p = stage[e];
        int pos = atomicAdd(&lcur[(p >> 17) & 255], 1);
        csr_src[pos] = p & 0x1FFFF;
    }
}

// ---------------- W1 frag pack + w2l + c0 + bucket_cur zero ------------------
__global__ void wfrag_k(const float* __restrict__ W1, const float* __restrict__ W2,
                        unsigned short* __restrict__ fw1, float* __restrict__ w2l,
                        const float* __restrict__ b2, const float* __restrict__ Wl,
                        const float* __restrict__ bl, float* __restrict__ c0,
                        int* __restrict__ bcur) {
    int gid = blockIdx.x * blockDim.x + threadIdx.x;
    if (gid < NBMAX) bcur[gid] = 0;                        // zero bucket counters
    if (blockIdx.x == 0 && threadIdx.x < 64) {             // c0 = dot(b2,Wl)+bl
        float v = b2[threadIdx.x] * Wl[threadIdx.x];
        #pragma unroll
        for (int m = 32; m >= 1; m >>= 1) v += __shfl_xor(v, m);
        if (threadIdx.x == 0) c0[0] = v + bl[0];
    }
    if (blockIdx.x == 1 && threadIdx.x < 64) {             // w2l = W2 @ Wl
        int k = threadIdx.x;
        float s = 0.f;
        #pragma unroll 8
        for (int j = 0; j < 64; ++j) s = fmaf(W2[k * 64 + j], Wl[j], s);
        w2l[k] = s;
    }
    if (gid < 8192) {                                      // W1 B-fragments
        int f = gid >> 9, rem = gid & 511;
        int l = rem >> 3, i = rem & 7;
        int ks = f >> 2, ct = f & 3;
        int k = ks * 32 + ((l >> 4) << 3) + i;
        int c = ct * 16 + (l & 15);
        fw1[gid] = f2b(W1[k * 64 + c]);
    }
}

// ---------------- MFMA GEMM1: Y[r,:] = bf16( dis[r] * (x[r,:] @ W1) ) --------
template <int K>
__global__ __launch_bounds__(256) void mfma_gemm_k(
    const float* __restrict__ X, const unsigned short* __restrict__ FW,
    const float* __restrict__ dis, unsigned short* __restrict__ Y, int n) {
    constexpr int KS = K / 32;
    int wave   = (int)((blockIdx.x * blockDim.x + threadIdx.x) >> 6);
    int lane   = threadIdx.x & 63;
    int nwaves = (int)((gridDim.x * blockDim.x) >> 6);
    int ntiles = n >> 4;

    bf16x8 bfrag[KS][4];
    #pragma unroll
    for (int ks = 0; ks < KS; ++ks)
        #pragma unroll
        for (int ct = 0; ct < 4; ++ct)
            bfrag[ks][ct] = *reinterpret_cast<const bf16x8*>(FW + ((ks * 4 + ct) << 9) + (lane << 3));

    int rb = lane & 15;
    int kb = (lane >> 4) << 3;

    for (int tile = wave; tile < ntiles; tile += nwaves) {
        int row = (tile << 4) + rb;
        f32x4 acc[4];
        #pragma unroll
        for (int ct = 0; ct < 4; ++ct) acc[ct] = (f32x4){0.f, 0.f, 0.f, 0.f};

        #pragma unroll
        for (int ks = 0; ks < KS; ++ks) {
            const float* p = X + (size_t)row * K + ks * 32 + kb;
            float4 u = *reinterpret_cast<const float4*>(p);
            float4 v = *reinterpret_cast<const float4*>(p + 4);
            bf16x8 af;
            af[0] = (short)f2b(u.x); af[1] = (short)f2b(u.y);
            af[2] = (short)f2b(u.z); af[3] = (short)f2b(u.w);
            af[4] = (short)f2b(v.x); af[5] = (short)f2b(v.y);
            af[6] = (short)f2b(v.z); af[7] = (short)f2b(v.w);
            #pragma unroll
            for (int ct = 0; ct < 4; ++ct)
                acc[ct] = __builtin_amdgcn_mfma_f32_16x16x32_bf16(af, bfrag[ks][ct], acc[ct], 0, 0, 0);
        }

        int orow0 = (tile << 4) + ((lane >> 4) << 2);
        int ocol  = lane & 15;
        float dv0 = dis[orow0], dv1 = dis[orow0 + 1], dv2 = dis[orow0 + 2], dv3 = dis[orow0 + 3];
        #pragma unroll
        for (int ct = 0; ct < 4; ++ct) {
            Y[(size_t)(orow0 + 0) * 64 + ct * 16 + ocol] = f2b(acc[ct][0] * dv0);
            Y[(size_t)(orow0 + 1) * 64 + ct * 16 + ocol] = f2b(acc[ct][1] * dv1);
            Y[(size_t)(orow0 + 2) * 64 + ct * 16 + ocol] = f2b(acc[ct][2] * dv2);
            Y[(size_t)(orow0 + 3) * 64 + ct * 16 + ocol] = f2b(acc[ct][3] * dv3);
        }
    }
}

// ---------------- fused gather1 + (relu, W2@Wl dot) -> z ---------------------
// Per node: agg = tp[node] + sum_{s in N} tp[s]  (tp rows pre-scaled by dis);
// h1 = relu(dd*agg + b1) in registers; z[node] = dd * dot(h1, w2l).
// Proven shape: 64 lanes/edge row-contiguous loads, 8 accumulators (VGPR 24).
__global__ __launch_bounds__(256) void gather_k(
    const int* __restrict__ row_start, const int* __restrict__ csr_src,
    const float* __restrict__ dis, const unsigned short* __restrict__ tp,
    const float* __restrict__ b, const float* __restrict__ w2l,
    float* __restrict__ z, int n) {
    int node = (int)((blockIdx.x * blockDim.x + threadIdx.x) >> 6);
    int lane = threadIdx.x & 63;
    if (node >= n) return;
    int beg = row_start[node], end = row_start[node + 1];
    float dd = dis[node];
    float a0 = b2f(tp[(size_t)node * 64 + lane]);   // self term (pre-scaled)
    float a1 = 0.f, a2 = 0.f, a3 = 0.f, a4 = 0.f, a5 = 0.f, a6 = 0.f, a7 = 0.f;

    for (int base = beg; base < end; base += 64) {
        int rem = end - base;
        int cnt = rem < 64 ? rem : 64;
        int idx = (lane < cnt) ? csr_src[base + lane] : 0;   // coalesced window
        int j = 0;
        for (; j + 8 <= cnt; j += 8) {
            int s0 = __shfl(idx, j + 0), s1 = __shfl(idx, j + 1);
            int s2 = __shfl(idx, j + 2), s3 = __shfl(idx, j + 3);
            int s4 = __shfl(idx, j + 4), s5 = __shfl(idx, j + 5);
            int s6 = __shfl(idx, j + 6), s7 = __shfl(idx, j + 7);
            a0 += b2f(tp[(size_t)s0 * 64 + lane]);
            a1 += b2f(tp[(size_t)s1 * 64 + lane]);
            a2 += b2f(tp[(size_t)s2 * 64 + lane]);
            a3 += b2f(tp[(size_t)s3 * 64 + lane]);
            a4 += b2f(tp[(size_t)s4 * 64 + lane]);
            a5 += b2f(tp[(size_t)s5 * 64 + lane]);
            a6 += b2f(tp[(size_t)s6 * 64 + lane]);
            a7 += b2f(tp[(size_t)s7 * 64 + lane]);
        }
        if (j + 4 <= cnt) {
            int s0 = __shfl(idx, j + 0), s1 = __shfl(idx, j + 1);
            int s2 = __shfl(idx, j + 2), s3 = __shfl(idx, j + 3);
            a0 += b2f(tp[(size_t)s0 * 64 + lane]);
            a1 += b2f(tp[(size_t)s1 * 64 + lane]);
            a2 += b2f(tp[(size_t)s2 * 64 + lane]);
            a3 += b2f(tp[(size_t)s3 * 64 + lane]);
            j += 4;
        }
        for (; j < cnt; ++j) {
            int s = __shfl(idx, j);
            a4 += b2f(tp[(size_t)s * 64 + lane]);
        }
    }

    float acc = ((a0 + a1) + (a2 + a3)) + ((a4 + a5) + (a6 + a7));
    float h = fmaxf(fmaf(dd, acc, b[lane]), 0.f);   // h1[node][lane], fp32
    float v = h * w2l[lane];
    #pragma unroll
    for (int m = 32; m >= 1; m >>= 1) v += __shfl_xor(v, m);
    if (lane == 0) z[node] = dd * v;
}

// ---------------- layer-2 scalar gather + sigmoid (head folded) -------------
__global__ __launch_bounds__(256) void gatherz_k(
    const int* __restrict__ row_start, const int* __restrict__ csr_src,
    const float* __restrict__ dis, const float* __restrict__ z,
    const float* __restrict__ c0, float* __restrict__ out, int n) {
    int i = blockIdx.x * blockDim.x + threadIdx.x;
    if (i >= n) return;
    int beg = row_start[i], end = row_start[i + 1];
    float s0 = 0.f, s1 = 0.f, s2 = 0.f, s3 = 0.f;
    int e = beg;
    for (; e + 4 <= end; e += 4) {
        s0 += z[csr_src[e + 0]];
        s1 += z[csr_src[e + 1]];
        s2 += z[csr_src[e + 2]];
        s3 += z[csr_src[e + 3]];
    }
    for (; e < end; ++e) s0 += z[csr_src[e]];
    float v = fmaf(dis[i], z[i] + ((s0 + s1) + (s2 + s3)), c0[0]);
    out[i] = 1.f / (1.f + expf(-v));
}

// ---------------- fallback kernels (only if ws too small / shape odd) --------

__global__ void relu_k(float* __restrict__ p, long long m) {
    long long i = (long long)blockIdx.x * blockDim.x + threadIdx.x;
    if (i < m) p[i] = fmaxf(p[i], 0.f);
}
__global__ void deg_init_k(float* __restrict__ deg, int n) {
    int i = blockIdx.x * blockDim.x + threadIdx.x;
    if (i < n) deg[i] = 1.0f;
}
__global__ void deg_edges_k(const int* __restrict__ dst, float* __restrict__ deg, int E) {
    int e = blockIdx.x * blockDim.x + threadIdx.x;
    if (e < E) atomicAdd(&deg[dst[e]], 1.0f);
}
__global__ void dis_k(float* __restrict__ deg, int n) {
    int i = blockIdx.x * blockDim.x + threadIdx.x;
    if (i < n) deg[i] = rsqrtf(deg[i]);
}
__global__ void init_agg_k(const float* __restrict__ t, const float* __restrict__ dis,
                           const float* __restrict__ b, float* __restrict__ agg, int n) {
    int idx = blockIdx.x * blockDim.x + threadIdx.x;
    if (idx >= n * 64) return;
    int i = idx >> 6, jj = idx & 63;
    float ds = dis[i];
    agg[idx] = ds * ds * t[idx] + b[jj];
}
__global__ __launch_bounds__(256) void agg_edges_k(
    const int* __restrict__ src, const int* __restrict__ dst,
    const float* __restrict__ dis, const float* __restrict__ t,
    float* __restrict__ agg, int E) {
    int e    = (int)((blockIdx.x * blockDim.x + threadIdx.x) >> 6);
    int lane = threadIdx.x & 63;
    if (e >= E) return;
    int s = src[e], d = dst[e];
    float w = dis[s] * dis[d];
    atomicAdd(&agg[(size_t)d * 64 + lane], w * t[(size_t)s * 64 + lane]);
}
__global__ __launch_bounds__(256) void final_k(
    const float* __restrict__ agg, const float* __restrict__ Wl,
    const float* __restrict__ bl, float* __restrict__ out, int n) {
    int node = (int)((blockIdx.x * blockDim.x + threadIdx.x) >> 6);
    int lane = threadIdx.x & 63;
    if (node >= n) return;
    float v = agg[(size_t)node * 64 + lane] * Wl[lane];
    #pragma unroll
    for (int m = 32; m >= 1; m >>= 1) v += __shfl_xor(v, m);
    if (lane == 0) out[node] = 1.f / (1.f + expf(-(v + bl[0])));
}
template <int K>
__global__ __launch_bounds__(256) void gemm_rows4_k(
    const float* __restrict__ X, const float* __restrict__ W,
    float* __restrict__ Y, int n) {
    __shared__ float Ws[K * 64];
    for (int t = threadIdx.x; t < K * 64; t += blockDim.x) Ws[t] = W[t];
    __syncthreads();
    int wave   = (int)((blockIdx.x * blockDim.x + threadIdx.x) >> 6);
    int lane   = threadIdx.x & 63;
    int nwaves = (int)((gridDim.x * blockDim.x) >> 6);
    for (int r = wave; r < n; r += nwaves) {
        const float* xr = X + (size_t)r * K;
        float acc = 0.f;
        for (int k = 0; k < K; k += 4) {
            float4 a = *reinterpret_cast<const float4*>(xr + k);
            acc = fmaf(a.x, Ws[(k + 0) * 64 + lane], acc);
            acc = fmaf(a.y, Ws[(k + 1) * 64 + lane], acc);
            acc = fmaf(a.z, Ws[(k + 2) * 64 + lane], acc);
            acc = fmaf(a.w, Ws[(k + 3) * 64 + lane], acc);
        }
        Y[(size_t)r * 64 + lane] = acc;
    }
}

// ---------------------------------------------------------------------------

extern "C" void kernel_launch(void* const* d_in, const int* in_sizes, int n_in,
                              void* d_out, int out_size, void* d_ws, size_t ws_size,
                              hipStream_t stream) {
    const float* x  = (const float*)d_in[0];
    const int*   ei = (const int*)d_in[1];
    const float* W1 = (const float*)d_in[2];
    const float* b1 = (const float*)d_in[3];
    const float* W2 = (const float*)d_in[4];
    const float* b2 = (const float*)d_in[5];
    const float* Wl = (const float*)d_in[6];
    const float* bl = (const float*)d_in[7];
    float* out = (float*)d_out;

    const int n = in_sizes[0] / 128;      // 100000
    const int E = in_sizes[1] / 2;        // 1600000
    const int* src = ei;
    const int* dst = ei + E;

    const int B = 256;
    dim3 blk(B);
    auto align512 = [](size_t v) { return (v + 511) & ~(size_t)511; };

    const int nbuckets = (n + 255) >> 8;
    // bin capacity: mean + ~16 sigma for Poisson bucket loads, 64-aligned
    const int CAP = nbuckets > 0 ? (((E / nbuckets) + 1024 + 63) & ~63) : 0;

    // workspace layout
    char* ws = (char*)d_ws;
    size_t off = 0;
    float*          dis     = (float*)(ws + off); off = align512(off + (size_t)n * 4);
    int*            row_st  = (int*)  (ws + off); off = align512(off + (size_t)(n + 1) * 4);
    int*            bcur    = (int*)  (ws + off); off = align512(off + (size_t)NBMAX * 4);
    float*          c0      = (float*)(ws + off); off = align512(off + 512);
    float*          w2l     = (float*)(ws + off); off = align512(off + 64 * 4);
    float*          zbuf    = (float*)(ws + off); off = align512(off + (size_t)n * 4);
    int*            csr_src = (int*)  (ws + off); off = align512(off + (size_t)E * 4);
    unsigned short* bufA16  = (unsigned short*)(ws + off); off = align512(off + (size_t)n * 64 * 2);
    int*            stage   = (int*)  (ws + off); off = align512(off + (size_t)nbuckets * CAP * 4);
    unsigned short* fw1     = (unsigned short*)(ws + off); off = align512(off + 8192 * 2);
    size_t need_csr = off;

    const int nebl = (E + EPB - 1) / EPB;   // edge blocks

    if (ws_size >= need_csr && (n & 15) == 0 && nbuckets <= NBMAX && n <= (1 << 17)) {
        // ---- W1 frag pack + w2l + c0 + bucket_cur zero (one small launch) ----
        wfrag_k<<<48, blk, 0, stream>>>(W1, W2, fw1, w2l, b2, Wl, bl, c0, bcur);

        // ---- CSR build: bins -> (row_start, dis, csr) ----
        partition_k<<<nebl, blk, 0, stream>>>(src, dst, bcur, stage, E, nbuckets, CAP);
        bucket_place_k<<<nbuckets, blk, 0, stream>>>(stage, bcur, row_st, dis, csr_src, n, nbuckets, CAP);

        int gemm_blocks = ((n >> 4) + 3) / 4;   // one wave per 16-row tile

        // ---- layer 1 GEMM: bufA16 = bf16(dis * (x @ W1)) ----
        mfma_gemm_k<128><<<gemm_blocks, blk, 0, stream>>>(x, fw1, dis, bufA16, n);

        // ---- fused gather1 + relu + (W2@Wl) dot -> z ----
        gather_k<<<((size_t)n * 64 + B - 1) / B, blk, 0, stream>>>(
            row_st, csr_src, dis, bufA16, b1, w2l, zbuf, n);

        // ---- layer-2 scalar aggregation + sigmoid ----
        gatherz_k<<<(n + B - 1) / B, blk, 0, stream>>>(
            row_st, csr_src, dis, zbuf, c0, out, n);
    } else {
        // ---- fallback: atomic scatter, fp32 GEMM ----
        size_t o2 = 0;
        float* dis2 = (float*)(ws + o2); o2 = align512(o2 + (size_t)n * 4);
        float* bA   = (float*)(ws + o2); o2 += (size_t)n * 64 * 4;
        float* bB   = (float*)(ws + o2);

        deg_init_k<<<(n + B - 1) / B, blk, 0, stream>>>(dis2, n);
        deg_edges_k<<<(E + B - 1) / B, blk, 0, stream>>>(dst, dis2, E);
        dis_k<<<(n + B - 1) / B, blk, 0, stream>>>(dis2, n);

        gemm_rows4_k<128><<<2048, blk, 0, stream>>>(x, W1, bA, n);
        init_agg_k<<<((size_t)n * 64 + B - 1) / B, blk, 0, stream>>>(bA, dis2, b1, bB, n);
        agg_edges_k<<<(E + 3) / 4, blk, 0, stream>>>(src, dst, dis2, bA, bB, E);
        relu_k<<<((size_t)n * 64 + B - 1) / B, blk, 0, stream>>>(bB, (long long)n * 64);

        gemm_rows4_k<64><<<2048, blk, 0, stream>>>(bB, W2, bA, n);
        init_agg_k<<<((size_t)n * 64 + B - 1) / B, blk, 0, stream>>>(bA, dis2, b2, bB, n);
        agg_edges_k<<<(E + 3) / 4, blk, 0, stream>>>(src, dst, dis2, bA, bB, E);

        final_k<<<(n + 3) / 4, blk, 0, stream>>>(bB, Wl, bl, out, n);
    }
}